// Round 1
// baseline (310.199 us; speedup 1.0000x reference)
//
#include <hip/hip_runtime.h>

#define NB   64
#define CIN  128
#define COUT 128
#define HH   64
#define WW   64
#define HW   4096   // 64*64
#define HID  8

// -------- workspace layout (floats) --------
// bs : [N][CIN][16]   off 0       size 131072   (16x16 block sums)
// co : [N][COUT]      off 131072  size 8192
// ci : [N][CIN]       off 139264  size 8192
// sp : [N][16]        off 147456  size 1024     (9 used per sample)
// t  : [N][HW]        off 148480  size 262144

// K1: per-(n,c) plane -> 16 block sums (each over a 16x16 region)
__global__ __launch_bounds__(256) void k_blocksums(const float* __restrict__ x,
                                                   float* __restrict__ bs) {
    const int plane = blockIdx.x;           // n*CIN + c
    const int tid = threadIdx.x;
    const int r = tid >> 2;                 // row 0..63
    const int q = tid & 3;                  // 16-col quarter 0..3
    const float4* p = (const float4*)(x + (size_t)plane * HW + r * WW + q * 16);
    float4 a = p[0], b = p[1], c = p[2], d = p[3];
    float s = a.x + a.y + a.z + a.w + b.x + b.y + b.z + b.w
            + c.x + c.y + c.z + c.w + d.x + d.y + d.z + d.w;
    __shared__ float part[256];
    part[tid] = s;
    __syncthreads();
    if (tid < 16) {
        const int br = tid >> 2, qq = tid & 3;   // row-block, col-block
        float acc = 0.0f;
        #pragma unroll
        for (int i = 0; i < 16; ++i) acc += part[(br * 16 + i) * 4 + qq];
        bs[plane * 16 + br * 4 + qq] = acc;      // j = a*4 + b  (matches reshape)
    }
}

// K2: per-sample stats + tiny MLPs -> co, ci, sp
__global__ __launch_bounds__(128) void k_coef(
    const float* __restrict__ bs,
    const float* __restrict__ W_sp, const float* __restrict__ b_sp,
    const float* __restrict__ W_o1, const float* __restrict__ b_o1,
    const float* __restrict__ W_o2, const float* __restrict__ b_o2,
    const float* __restrict__ W_i1, const float* __restrict__ b_i1,
    const float* __restrict__ W_i2, const float* __restrict__ b_i2,
    float* __restrict__ co, float* __restrict__ ci, float* __restrict__ sp)
{
    const int n = blockIdx.x, c = threadIdx.x;
    __shared__ float lbs[128][16];
    __shared__ float lgap[128];
    __shared__ float lxsm[16];
    __shared__ float lh[16];   // [0..7]=out-branch hidden, [8..15]=in-branch hidden

    const float* src = bs + ((size_t)n * CIN + c) * 16;
    float s = 0.0f;
    #pragma unroll
    for (int j = 0; j < 16; ++j) { float v = src[j]; lbs[c][j] = v; s += v; }
    lgap[c] = s * (1.0f / 4096.0f);          // gap[n,c] = mean over H,W
    __syncthreads();

    if (c < 16) {                             // xsm[j] = mean_c(bs/256)
        float acc = 0.0f;
        for (int i = 0; i < 128; ++i) acc += lbs[i][c];
        lxsm[c] = acc * (1.0f / 32768.0f);
    }
    if (c < 8) {
        float acc = b_o1[c];
        for (int i = 0; i < 128; ++i) acc += lgap[i] * W_o1[i * 8 + c];
        lh[c] = fmaxf(acc, 0.0f);
    } else if (c < 16) {
        const int j = c - 8;
        float acc = b_i1[j];
        for (int i = 0; i < 128; ++i) acc += lgap[i] * W_i1[i * 8 + j];
        lh[c] = fmaxf(acc, 0.0f);
    }
    __syncthreads();

    float acco = b_o2[c];
    float acci = b_i2[c];
    #pragma unroll
    for (int j = 0; j < 8; ++j) {
        acco += lh[j]     * W_o2[j * 128 + c];
        acci += lh[8 + j] * W_i2[j * 128 + c];
    }
    co[n * COUT + c] = acco;
    ci[n * CIN + c]  = acci;

    if (c < 9) {
        float acc = b_sp[c];
        #pragma unroll
        for (int j = 0; j < 16; ++j) acc += lxsm[j] * W_sp[j * 9 + c];
        sp[n * 16 + c] = acc;
    }
}

// K3: t[n,y,x] = sum_c ci[n,c] * x[n,c,y,x]   (second streaming read of x)
__global__ __launch_bounds__(256) void k_t(const float* __restrict__ x,
                                           const float* __restrict__ ci,
                                           float* __restrict__ t) {
    const int bid = blockIdx.x;          // N*4 blocks
    const int n = bid >> 2;
    const int y0 = (bid & 3) * 16;       // 16-row tile
    const int tid = threadIdx.x;
    const size_t base = (size_t)n * CIN * HW + (size_t)y0 * WW + (size_t)tid * 4;
    const float* cin = ci + n * CIN;

    float4 acc; acc.x = acc.y = acc.z = acc.w = 0.0f;
    for (int c = 0; c < CIN; c += 4) {
        float4 v0 = *(const float4*)(x + base + (size_t)(c + 0) * HW);
        float4 v1 = *(const float4*)(x + base + (size_t)(c + 1) * HW);
        float4 v2 = *(const float4*)(x + base + (size_t)(c + 2) * HW);
        float4 v3 = *(const float4*)(x + base + (size_t)(c + 3) * HW);
        const float c0 = cin[c], c1 = cin[c + 1], c2 = cin[c + 2], c3 = cin[c + 3];
        acc.x += v0.x * c0 + v1.x * c1 + v2.x * c2 + v3.x * c3;
        acc.y += v0.y * c0 + v1.y * c1 + v2.y * c2 + v3.y * c3;
        acc.z += v0.z * c0 + v1.z * c1 + v2.z * c2 + v3.z * c3;
        acc.w += v0.w * c0 + v1.w * c1 + v2.w * c2 + v3.w * c3;
    }
    *(float4*)(t + (size_t)n * HW + (size_t)y0 * WW + (size_t)tid * 4) = acc;
}

// K4: s = conv3x3(t, sp) (pad 1), out[n,o,y,x] = co[n,o] * s[n,y,x]
__global__ __launch_bounds__(256) void k_out(const float* __restrict__ t,
                                             const float* __restrict__ co,
                                             const float* __restrict__ sp,
                                             float* __restrict__ out) {
    const int bid = blockIdx.x;          // N*8 blocks
    const int n = bid >> 3;
    const int y0 = (bid & 7) * 8;        // 8-row tile
    const int tid = threadIdx.x;

    __shared__ float ts[10][64];         // rows y0-1 .. y0+8
    __shared__ float lco[128];
    __shared__ float lsp[9];

    if (tid < 128) lco[tid] = co[n * COUT + tid];
    if (tid < 9)  lsp[tid] = sp[n * 16 + tid];
    for (int k = tid; k < 640; k += 256) {
        const int ry = k >> 6, cx = k & 63;
        const int gy = y0 - 1 + ry;
        ts[ry][cx] = (gy >= 0 && gy < HH) ? t[(size_t)n * HW + gy * WW + cx] : 0.0f;
    }
    __syncthreads();

    const int i = tid & 127;             // float4 index in 8x64 tile
    const int row = i >> 4;              // 0..7
    const int c0 = (i & 15) * 4;
    float sv[4];
    #pragma unroll
    for (int u = 0; u < 4; ++u) {
        const int cc = c0 + u;
        float acc = 0.0f;
        #pragma unroll
        for (int dy = 0; dy < 3; ++dy) {
            #pragma unroll
            for (int dx = 0; dx < 3; ++dx) {
                const int cx = cc + dx - 1;
                if (cx >= 0 && cx < WW)
                    acc += lsp[dy * 3 + dx] * ts[row + dy][cx];
            }
        }
        sv[u] = acc;
    }

    const int ohalf = (tid >> 7) * 64;   // threads 0..127 -> o=op, 128..255 -> o=64+op
    float4* outp = (float4*)(out + (size_t)n * COUT * HW + (size_t)y0 * WW) + i;
    #pragma unroll 4
    for (int op = 0; op < 64; ++op) {
        const int o = ohalf + op;
        const float scl = lco[o];
        float4 v; v.x = sv[0] * scl; v.y = sv[1] * scl; v.z = sv[2] * scl; v.w = sv[3] * scl;
        outp[(size_t)o * (HW / 4)] = v;
    }
}

extern "C" void kernel_launch(void* const* d_in, const int* in_sizes, int n_in,
                              void* d_out, int out_size, void* d_ws, size_t ws_size,
                              hipStream_t stream) {
    const float* x    = (const float*)d_in[0];
    const float* W_sp = (const float*)d_in[1];
    const float* b_sp = (const float*)d_in[2];
    const float* W_o1 = (const float*)d_in[3];
    const float* b_o1 = (const float*)d_in[4];
    const float* W_o2 = (const float*)d_in[5];
    const float* b_o2 = (const float*)d_in[6];
    const float* W_i1 = (const float*)d_in[7];
    const float* b_i1 = (const float*)d_in[8];
    const float* W_i2 = (const float*)d_in[9];
    const float* W_i2b= (const float*)d_in[10];  // b_i2

    float* ws = (float*)d_ws;
    float* bs = ws;
    float* co = ws + 131072;
    float* ci = ws + 139264;
    float* sp = ws + 147456;
    float* t  = ws + 148480;
    float* out = (float*)d_out;

    k_blocksums<<<NB * CIN, 256, 0, stream>>>(x, bs);
    k_coef<<<NB, 128, 0, stream>>>(bs, W_sp, b_sp, W_o1, b_o1, W_o2, b_o2,
                                   W_i1, b_i1, W_i2, W_i2b, co, ci, sp);
    k_t<<<NB * 4, 256, 0, stream>>>(x, ci, t);
    k_out<<<NB * 8, 256, 0, stream>>>(t, co, sp, out);
}

// Round 2
// 284.369 us; speedup vs baseline: 1.0908x; 1.0908x over previous
//
#include <hip/hip_runtime.h>

#define NB   64
#define CIN  128
#define COUT 128
#define HH   64
#define WW   64
#define HW   4096

typedef float f4v __attribute__((ext_vector_type(4)));

// -------- workspace layout (float offsets) --------
// bs : [N][CIN][16]            @ 0       (131072)
// co : [N][128]                @ 131072  (8192)
// hi : [N][8]   (relu'd)       @ 139264  (512)
// sp : [N][16]  (9 used)       @ 139776  (1024)
// B  : [18][N][HW] basis flds  @ 147456  (4718592)   field f = p*9+j, p=channel half

// K1: single pass over x. Per block: (n, rowblock rb, channel-half p).
// Produces: bs[n, c, rb*4+cb] for its 64 channels, and basis fields
// B[p*9+j][n, 16-row slice] with j=0..7 -> W_i2 rows, j=8 -> b_i2.
__global__ __launch_bounds__(256) void k_stats(const float* __restrict__ x,
                                               const float* __restrict__ W_i2,
                                               const float* __restrict__ b_i2,
                                               float* __restrict__ bs,
                                               float* __restrict__ B) {
    const int bid = blockIdx.x;        // n*8 + rb*2 + p
    const int n  = bid >> 3;
    const int rb = (bid >> 1) & 3;
    const int p  = bid & 1;
    const int c0 = p * 64;
    const int tid = threadIdx.x;
    const int r = tid >> 4;            // 0..15 (row within 16-row tile)
    const int colq = tid & 15;         // float4 column
    const int y0 = rb * 16;

    __shared__ float lw[9][64];
    __shared__ float bsw[4][4][64];    // [wave][colblock][c]

    if (tid < 64) {
        lw[8][tid] = b_i2[c0 + tid];
        #pragma unroll
        for (int j = 0; j < 8; ++j) lw[j][tid] = W_i2[j * CIN + c0 + tid];
    }
    __syncthreads();

    float4 acc[9];
    #pragma unroll
    for (int j = 0; j < 9; ++j) acc[j] = make_float4(0.f, 0.f, 0.f, 0.f);

    const size_t xbase = ((size_t)n * CIN + c0) * HW + (size_t)(y0 + r) * WW + colq * 4;
    const int wv = tid >> 6;
    const int cb = colq >> 2;
    const bool rep = (tid & 0x33) == 0;   // bits {0,1,4,5} clear -> one lane per (wave,cb)

    for (int c = 0; c < 64; ++c) {
        float4 v = *(const float4*)(x + xbase + (size_t)c * HW);
        #pragma unroll
        for (int j = 0; j < 9; ++j) {
            const float w = lw[j][c];
            acc[j].x += w * v.x; acc[j].y += w * v.y;
            acc[j].z += w * v.z; acc[j].w += w * v.w;
        }
        float ls = (v.x + v.y) + (v.z + v.w);
        ls += __shfl_xor(ls, 1,  64);
        ls += __shfl_xor(ls, 2,  64);
        ls += __shfl_xor(ls, 16, 64);
        ls += __shfl_xor(ls, 32, 64);
        if (rep) bsw[wv][cb][c] = ls;
    }
    __syncthreads();

    {   // 256 outputs: c 0..63 x cb 0..3, reduce the 4 waves
        const int c = tid >> 2, cb2 = tid & 3;
        const float s = bsw[0][cb2][c] + bsw[1][cb2][c] + bsw[2][cb2][c] + bsw[3][cb2][c];
        bs[((size_t)n * CIN + c0 + c) * 16 + rb * 4 + cb2] = s;
    }

    const size_t bpix = (size_t)(y0 + r) * WW + colq * 4;
    #pragma unroll
    for (int j = 0; j < 9; ++j) {
        *(float4*)(B + ((size_t)(p * 9 + j) * NB + n) * HW + bpix) = acc[j];
    }
}

// K2: per-sample MLPs -> co[128], hi[8] (relu'd in-branch hidden), sp[9]
__global__ __launch_bounds__(128) void k_coef(
    const float* __restrict__ bs,
    const float* __restrict__ W_sp, const float* __restrict__ b_sp,
    const float* __restrict__ W_o1, const float* __restrict__ b_o1,
    const float* __restrict__ W_o2, const float* __restrict__ b_o2,
    const float* __restrict__ W_i1, const float* __restrict__ b_i1,
    float* __restrict__ co, float* __restrict__ hi, float* __restrict__ sp)
{
    const int n = blockIdx.x, c = threadIdx.x;
    __shared__ float lbs[128][17];
    __shared__ float lgap[128];
    __shared__ float lxsm[16];
    __shared__ float lh[16];

    const float* src = bs + ((size_t)n * CIN + c) * 16;
    float s = 0.0f;
    #pragma unroll
    for (int j = 0; j < 16; ++j) { const float v = src[j]; lbs[c][j] = v; s += v; }
    lgap[c] = s * (1.0f / 4096.0f);
    __syncthreads();

    if (c < 16) {
        float acc = 0.0f;
        for (int i = 0; i < 128; ++i) acc += lbs[i][c];
        lxsm[c] = acc * (1.0f / 32768.0f);
    }
    if (c < 8) {
        float acc = b_o1[c];
        for (int i = 0; i < 128; ++i) acc += lgap[i] * W_o1[i * 8 + c];
        lh[c] = fmaxf(acc, 0.0f);
    } else if (c < 16) {
        const int j = c - 8;
        float acc = b_i1[j];
        for (int i = 0; i < 128; ++i) acc += lgap[i] * W_i1[i * 8 + j];
        lh[c] = fmaxf(acc, 0.0f);
    }
    __syncthreads();

    float acco = b_o2[c];
    #pragma unroll
    for (int j = 0; j < 8; ++j) acco += lh[j] * W_o2[j * 128 + c];
    co[n * COUT + c] = acco;

    if (c < 8) hi[n * 8 + c] = lh[8 + c];
    if (c < 9) {
        float acc = b_sp[c];
        #pragma unroll
        for (int j = 0; j < 16; ++j) acc += lxsm[j] * W_sp[j * 9 + c];
        sp[n * 16 + c] = acc;
    }
}

// K3: t-tile from basis fields (+halo), 3x3 stencil, scale by co[o], store.
__global__ __launch_bounds__(256) void k_out(const float* __restrict__ B,
                                             const float* __restrict__ co,
                                             const float* __restrict__ hi,
                                             const float* __restrict__ sp,
                                             float* __restrict__ out) {
    const int bid = blockIdx.x;          // n*8 + ytile
    const int n  = bid >> 3;
    const int y0 = (bid & 7) * 8;
    const int tid = threadIdx.x;

    __shared__ float ts[10][66];
    __shared__ float lco[128];
    __shared__ float lsp[9];
    __shared__ float lhi[8];

    if (tid < 128) lco[tid] = co[n * COUT + tid];
    if (tid < 9)  lsp[tid] = sp[n * 16 + tid];
    if (tid < 8)  lhi[tid] = hi[n * 8 + tid];
    __syncthreads();

    // build rows y0-1 .. y0+8 of t (160 float4s)
    if (tid < 160) {
        const int ry = tid >> 4, cq = tid & 15;
        const int gy = y0 - 1 + ry;
        float4 tv = make_float4(0.f, 0.f, 0.f, 0.f);
        if (gy >= 0 && gy < HH) {
            const size_t pix = (size_t)gy * WW + cq * 4;
            const float* Bn = B + (size_t)n * HW + pix;
            float4 a = *(const float4*)(Bn + (size_t)8  * NB * HW);
            float4 b = *(const float4*)(Bn + (size_t)17 * NB * HW);
            tv.x = a.x + b.x; tv.y = a.y + b.y; tv.z = a.z + b.z; tv.w = a.w + b.w;
            #pragma unroll
            for (int j = 0; j < 8; ++j) {
                const float h = lhi[j];
                float4 u = *(const float4*)(Bn + (size_t)j * NB * HW);
                float4 w = *(const float4*)(Bn + (size_t)(9 + j) * NB * HW);
                tv.x += h * (u.x + w.x); tv.y += h * (u.y + w.y);
                tv.z += h * (u.z + w.z); tv.w += h * (u.w + w.w);
            }
        }
        ts[ry][cq * 4 + 0] = tv.x; ts[ry][cq * 4 + 1] = tv.y;
        ts[ry][cq * 4 + 2] = tv.z; ts[ry][cq * 4 + 3] = tv.w;
    }
    __syncthreads();

    const int i = tid & 127;             // float4 index in 8x64 tile
    const int row = i >> 4;
    const int cc0 = (i & 15) * 4;
    float sv[4];
    #pragma unroll
    for (int u = 0; u < 4; ++u) {
        const int cc = cc0 + u;
        float acc = 0.0f;
        #pragma unroll
        for (int dy = 0; dy < 3; ++dy) {
            #pragma unroll
            for (int dx = 0; dx < 3; ++dx) {
                const int cx = cc + dx - 1;
                if (cx >= 0 && cx < WW)
                    acc += lsp[dy * 3 + dx] * ts[row + dy][cx];
            }
        }
        sv[u] = acc;
    }

    const int ohalf = (tid >> 7) * 64;
    float* outp = out + (size_t)n * COUT * HW + (size_t)y0 * WW + (size_t)i * 4;
    #pragma unroll 4
    for (int op = 0; op < 64; ++op) {
        const int o = ohalf + op;
        const float scl = lco[o];
        f4v v; v.x = sv[0] * scl; v.y = sv[1] * scl; v.z = sv[2] * scl; v.w = sv[3] * scl;
        __builtin_nontemporal_store(v, (f4v*)(outp + (size_t)o * HW));
    }
}

extern "C" void kernel_launch(void* const* d_in, const int* in_sizes, int n_in,
                              void* d_out, int out_size, void* d_ws, size_t ws_size,
                              hipStream_t stream) {
    const float* x    = (const float*)d_in[0];
    const float* W_sp = (const float*)d_in[1];
    const float* b_sp = (const float*)d_in[2];
    const float* W_o1 = (const float*)d_in[3];
    const float* b_o1 = (const float*)d_in[4];
    const float* W_o2 = (const float*)d_in[5];
    const float* b_o2 = (const float*)d_in[6];
    const float* W_i1 = (const float*)d_in[7];
    const float* b_i1 = (const float*)d_in[8];
    const float* W_i2 = (const float*)d_in[9];
    const float* b_i2 = (const float*)d_in[10];

    float* ws = (float*)d_ws;
    float* bs = ws;
    float* co = ws + 131072;
    float* hi = ws + 139264;
    float* sp = ws + 139776;
    float* B  = ws + 147456;
    float* out = (float*)d_out;

    k_stats<<<NB * 8, 256, 0, stream>>>(x, W_i2, b_i2, bs, B);
    k_coef<<<NB, 128, 0, stream>>>(bs, W_sp, b_sp, W_o1, b_o1, W_o2, b_o2,
                                   W_i1, b_i1, co, hi, sp);
    k_out<<<NB * 8, 256, 0, stream>>>(B, co, hi, sp, out);
}

// Round 3
// 283.745 us; speedup vs baseline: 1.0932x; 1.0022x over previous
//
#include <hip/hip_runtime.h>

#define NB   64
#define CIN  128
#define COUT 128
#define HH   64
#define WW   64
#define HW   4096

typedef float f4v __attribute__((ext_vector_type(4)));

// -------- workspace layout (float offsets) --------
// bs : [N][CIN][16]            @ 0       (131072)
// B  : [18][N][HW] basis flds  @ 147456  (4718592)   field f = p*9+j, p=channel half

// K1: single pass over x. Per block: (n, rowblock rb, channel-half p).
// Produces: bs[n, c, rb*4+cb] for its 64 channels, and basis fields
// B[p*9+j][n, 16-row slice] with j=0..7 -> W_i2 rows, j=8 -> b_i2.
__global__ __launch_bounds__(256) void k_stats(const float* __restrict__ x,
                                               const float* __restrict__ W_i2,
                                               const float* __restrict__ b_i2,
                                               float* __restrict__ bs,
                                               float* __restrict__ B) {
    const int bid = blockIdx.x;        // n*8 + rb*2 + p
    const int n  = bid >> 3;
    const int rb = (bid >> 1) & 3;
    const int p  = bid & 1;
    const int c0 = p * 64;
    const int tid = threadIdx.x;
    const int r = tid >> 4;            // 0..15 (row within 16-row tile)
    const int colq = tid & 15;         // float4 column
    const int y0 = rb * 16;

    __shared__ float lw[9][64];
    __shared__ float bsw[4][4][64];    // [wave][colblock][c]

    if (tid < 64) {
        lw[8][tid] = b_i2[c0 + tid];
        #pragma unroll
        for (int j = 0; j < 8; ++j) lw[j][tid] = W_i2[j * CIN + c0 + tid];
    }
    __syncthreads();

    float4 acc[9];
    #pragma unroll
    for (int j = 0; j < 9; ++j) acc[j] = make_float4(0.f, 0.f, 0.f, 0.f);

    const size_t xbase = ((size_t)n * CIN + c0) * HW + (size_t)(y0 + r) * WW + colq * 4;
    const int wv = tid >> 6;
    const int cb = colq >> 2;
    const bool rep = (tid & 0x33) == 0;   // one lane per (wave, colblock)

    for (int c = 0; c < 64; ++c) {
        f4v v = __builtin_nontemporal_load((const f4v*)(x + xbase + (size_t)c * HW));
        #pragma unroll
        for (int j = 0; j < 9; ++j) {
            const float w = lw[j][c];
            acc[j].x += w * v.x; acc[j].y += w * v.y;
            acc[j].z += w * v.z; acc[j].w += w * v.w;
        }
        float ls = (v.x + v.y) + (v.z + v.w);
        ls += __shfl_xor(ls, 1,  64);
        ls += __shfl_xor(ls, 2,  64);
        ls += __shfl_xor(ls, 16, 64);
        ls += __shfl_xor(ls, 32, 64);
        if (rep) bsw[wv][cb][c] = ls;
    }
    __syncthreads();

    {   // 256 outputs: c 0..63 x cb 0..3, reduce the 4 waves
        const int c = tid >> 2, cb2 = tid & 3;
        const float s = bsw[0][cb2][c] + bsw[1][cb2][c] + bsw[2][cb2][c] + bsw[3][cb2][c];
        bs[((size_t)n * CIN + c0 + c) * 16 + rb * 4 + cb2] = s;
    }

    const size_t bpix = (size_t)(y0 + r) * WW + colq * 4;
    #pragma unroll
    for (int j = 0; j < 9; ++j) {
        *(float4*)(B + ((size_t)(p * 9 + j) * NB + n) * HW + bpix) = acc[j];
    }
}

// K2 (fused): per-block coef prologue (co/hi/sp from bs), then t-tile from
// basis fields (+halo), 3x3 stencil, scale by co[o], nontemporal store.
__global__ __launch_bounds__(256) void k_out(
    const float* __restrict__ B, const float* __restrict__ bs,
    const float* __restrict__ W_sp, const float* __restrict__ b_sp,
    const float* __restrict__ W_o1, const float* __restrict__ b_o1,
    const float* __restrict__ W_o2, const float* __restrict__ b_o2,
    const float* __restrict__ W_i1, const float* __restrict__ b_i1,
    float* __restrict__ out)
{
    const int bid = blockIdx.x;          // n*8 + ytile
    const int n  = bid >> 3;
    const int y0 = (bid & 7) * 8;
    const int tid = threadIdx.x;

    __shared__ float lbs[128][17];
    __shared__ float lgap[128];
    __shared__ float lxsm[16];
    __shared__ float lh[16];             // [0..7] out-hidden, [8..15] in-hidden
    __shared__ float lco[128];
    __shared__ float lsp[9];
    __shared__ float ts[10][66];

    // ---- coef prologue (same math/order as the old k_coef) ----
    if (tid < 128) {
        const int c = tid;
        const float* src = bs + ((size_t)n * CIN + c) * 16;
        float s = 0.0f;
        #pragma unroll
        for (int j = 0; j < 16; ++j) { const float v = src[j]; lbs[c][j] = v; s += v; }
        lgap[c] = s * (1.0f / 4096.0f);
    }
    __syncthreads();

    if (tid < 16) {
        float acc = 0.0f;
        for (int i = 0; i < 128; ++i) acc += lbs[i][tid];
        lxsm[tid] = acc * (1.0f / 32768.0f);
    }
    if (tid < 8) {
        float acc = b_o1[tid];
        for (int i = 0; i < 128; ++i) acc += lgap[i] * W_o1[i * 8 + tid];
        lh[tid] = fmaxf(acc, 0.0f);
    } else if (tid < 16) {
        const int j = tid - 8;
        float acc = b_i1[j];
        for (int i = 0; i < 128; ++i) acc += lgap[i] * W_i1[i * 8 + j];
        lh[tid] = fmaxf(acc, 0.0f);
    }
    __syncthreads();

    if (tid < 128) {
        float acco = b_o2[tid];
        #pragma unroll
        for (int j = 0; j < 8; ++j) acco += lh[j] * W_o2[j * 128 + tid];
        lco[tid] = acco;
    }
    if (tid < 9) {
        float acc = b_sp[tid];
        #pragma unroll
        for (int j = 0; j < 16; ++j) acc += lxsm[j] * W_sp[j * 9 + tid];
        lsp[tid] = acc;
    }

    // ---- build rows y0-1 .. y0+8 of t (160 float4s) ----
    // lh[8..15] ready after the barrier below
    __syncthreads();
    if (tid < 160) {
        const int ry = tid >> 4, cq = tid & 15;
        const int gy = y0 - 1 + ry;
        float4 tv = make_float4(0.f, 0.f, 0.f, 0.f);
        if (gy >= 0 && gy < HH) {
            const size_t pix = (size_t)gy * WW + cq * 4;
            const float* Bn = B + (size_t)n * HW + pix;
            float4 a = *(const float4*)(Bn + (size_t)8  * NB * HW);
            float4 b = *(const float4*)(Bn + (size_t)17 * NB * HW);
            tv.x = a.x + b.x; tv.y = a.y + b.y; tv.z = a.z + b.z; tv.w = a.w + b.w;
            #pragma unroll
            for (int j = 0; j < 8; ++j) {
                const float h = lh[8 + j];
                float4 u = *(const float4*)(Bn + (size_t)j * NB * HW);
                float4 w = *(const float4*)(Bn + (size_t)(9 + j) * NB * HW);
                tv.x += h * (u.x + w.x); tv.y += h * (u.y + w.y);
                tv.z += h * (u.z + w.z); tv.w += h * (u.w + w.w);
            }
        }
        ts[ry][cq * 4 + 0] = tv.x; ts[ry][cq * 4 + 1] = tv.y;
        ts[ry][cq * 4 + 2] = tv.z; ts[ry][cq * 4 + 3] = tv.w;
    }
    __syncthreads();

    const int i = tid & 127;             // float4 index in 8x64 tile
    const int row = i >> 4;
    const int cc0 = (i & 15) * 4;
    float sv[4];
    #pragma unroll
    for (int u = 0; u < 4; ++u) {
        const int cc = cc0 + u;
        float acc = 0.0f;
        #pragma unroll
        for (int dy = 0; dy < 3; ++dy) {
            #pragma unroll
            for (int dx = 0; dx < 3; ++dx) {
                const int cx = cc + dx - 1;
                if (cx >= 0 && cx < WW)
                    acc += lsp[dy * 3 + dx] * ts[row + dy][cx];
            }
        }
        sv[u] = acc;
    }

    const int ohalf = (tid >> 7) * 64;
    float* outp = out + (size_t)n * COUT * HW + (size_t)y0 * WW + (size_t)i * 4;
    #pragma unroll 4
    for (int op = 0; op < 64; ++op) {
        const int o = ohalf + op;
        const float scl = lco[o];
        f4v v; v.x = sv[0] * scl; v.y = sv[1] * scl; v.z = sv[2] * scl; v.w = sv[3] * scl;
        __builtin_nontemporal_store(v, (f4v*)(outp + (size_t)o * HW));
    }
}

extern "C" void kernel_launch(void* const* d_in, const int* in_sizes, int n_in,
                              void* d_out, int out_size, void* d_ws, size_t ws_size,
                              hipStream_t stream) {
    const float* x    = (const float*)d_in[0];
    const float* W_sp = (const float*)d_in[1];
    const float* b_sp = (const float*)d_in[2];
    const float* W_o1 = (const float*)d_in[3];
    const float* b_o1 = (const float*)d_in[4];
    const float* W_o2 = (const float*)d_in[5];
    const float* b_o2 = (const float*)d_in[6];
    const float* W_i1 = (const float*)d_in[7];
    const float* b_i1 = (const float*)d_in[8];
    const float* W_i2 = (const float*)d_in[9];
    const float* b_i2 = (const float*)d_in[10];

    float* ws = (float*)d_ws;
    float* bs = ws;
    float* B  = ws + 147456;
    float* out = (float*)d_out;

    k_stats<<<NB * 8, 256, 0, stream>>>(x, W_i2, b_i2, bs, B);
    k_out<<<NB * 8, 256, 0, stream>>>(B, bs, W_sp, b_sp, W_o1, b_o1,
                                      W_o2, b_o2, W_i1, b_i1, out);
}